// Round 1
// 825.837 us; speedup vs baseline: 1.0477x; 1.0477x over previous
//
#include <hip/hip_runtime.h>
#include <stdint.h>

#define NNODES 20000
#define NEDGES 160000
#define NPAD   20096   // 157 * 128

typedef float f32x4 __attribute__((ext_vector_type(4)));
typedef float f32x2 __attribute__((ext_vector_type(2)));
typedef short s16x8 __attribute__((ext_vector_type(8)));

__device__ __forceinline__ float b2f(unsigned short b) {
    unsigned int u = ((unsigned int)b) << 16;
    return __builtin_bit_cast(float, u);
}
__device__ __forceinline__ unsigned short f2b(float f) {
    unsigned int u = __builtin_bit_cast(unsigned int, f);
    unsigned int r = (u + 0x7FFFu + ((u >> 16) & 1u)) >> 16;
    return (unsigned short)r;
}
// unpack 2 bf16 (packed in a dword) -> float2
__device__ __forceinline__ f32x2 unpack2(unsigned int u) {
    f32x2 r;
    r.x = __builtin_bit_cast(float, u << 16);
    r.y = __builtin_bit_cast(float, u & 0xFFFF0000u);
    return r;
}

// ---- GEMM: C[M,N] = A[M,K](bf16) @ BT[N,K]^T(bf16); C fp32 or bf16 ----
__global__ __launch_bounds__(256) void gemm_bt_kernel(
    const unsigned short* __restrict__ A,
    const unsigned short* __restrict__ BT,
    float* __restrict__ Cf,
    unsigned short* __restrict__ Cb,
    int M, int N, int K,
    const float* __restrict__ bias)
{
    __shared__ unsigned short As[128 * 32];
    __shared__ unsigned short Bs[128 * 32];
    const int tid  = threadIdx.x;
    const int wid  = tid >> 6;
    const int lane = tid & 63;
    const int bm = blockIdx.x * 128;
    const int bn = blockIdx.y * 128;
    const int wm = (wid & 1) * 64;
    const int wn = (wid >> 1) * 64;

    f32x4 acc[4][4];
#pragma unroll
    for (int i = 0; i < 4; i++)
#pragma unroll
        for (int j = 0; j < 4; j++) acc[i][j] = {0.f, 0.f, 0.f, 0.f};

    for (int k0 = 0; k0 < K; k0 += 32) {
#pragma unroll
        for (int r = 0; r < 2; r++) {
            int flat = r * 256 + tid;
            int row  = flat >> 2;
            int part = flat & 3;
            const unsigned short* ga = A  + (size_t)(bm + row) * K + k0 + part * 8;
            const unsigned short* gb = BT + (size_t)(bn + row) * K + k0 + part * 8;
            __builtin_amdgcn_global_load_lds(
                (const __attribute__((address_space(1))) unsigned int*)ga,
                (__attribute__((address_space(3))) unsigned int*)&As[flat * 8], 16, 0, 0);
            __builtin_amdgcn_global_load_lds(
                (const __attribute__((address_space(1))) unsigned int*)gb,
                (__attribute__((address_space(3))) unsigned int*)&Bs[flat * 8], 16, 0, 0);
        }
        __syncthreads();

        const int kq = (lane >> 4) * 8;
        const int rl = lane & 15;
        s16x8 af[4], bfr[4];
#pragma unroll
        for (int mi = 0; mi < 4; mi++)
            af[mi] = *(const s16x8*)&As[(wm + mi * 16 + rl) * 32 + kq];
#pragma unroll
        for (int ni = 0; ni < 4; ni++)
            bfr[ni] = *(const s16x8*)&Bs[(wn + ni * 16 + rl) * 32 + kq];
#pragma unroll
        for (int mi = 0; mi < 4; mi++)
#pragma unroll
            for (int ni = 0; ni < 4; ni++)
                acc[mi][ni] = __builtin_amdgcn_mfma_f32_16x16x32_bf16(
                    af[mi], bfr[ni], acc[mi][ni], 0, 0, 0);
        __syncthreads();
    }

    const int cl = lane & 15;
    const int rq = (lane >> 4) * 4;
#pragma unroll
    for (int mi = 0; mi < 4; mi++)
#pragma unroll
        for (int ni = 0; ni < 4; ni++)
#pragma unroll
            for (int r = 0; r < 4; r++) {
                int row = bm + wm + mi * 16 + rq + r;
                int col = bn + wn + ni * 16 + cl;
                float v = acc[mi][ni][r];
                if (Cb) {
                    if (bias) v = fmaxf(v + bias[col], 0.f);
                    Cb[(size_t)row * N + col] = f2b(v);
                } else {
                    Cf[(size_t)row * N + col] = v;
                }
            }
}

// ---------------- CSR build ----------------
__global__ void count_kernel(const int* __restrict__ ei, int* __restrict__ counts) {
    int e = blockIdx.x * blockDim.x + threadIdx.x;
    if (e < NEDGES) atomicAdd(&counts[ei[NEDGES + e]], 1);
}

__global__ __launch_bounds__(1024) void scan_kernel(const int* __restrict__ counts,
                                                    int* __restrict__ row_ptr)
{
    __shared__ int sdata[1024];
    const int t = threadIdx.x;
    int vals[20];
    const int base = t * 20;
    int lsum = 0;
#pragma unroll
    for (int j = 0; j < 20; j++) {
        int idx = base + j;
        int v = (idx < NNODES) ? counts[idx] : 0;
        vals[j] = v; lsum += v;
    }
    sdata[t] = lsum;
    __syncthreads();
    for (int off = 1; off < 1024; off <<= 1) {
        int v = (t >= off) ? sdata[t - off] : 0;
        __syncthreads();
        sdata[t] += v;
        __syncthreads();
    }
    int run = sdata[t] - lsum;
#pragma unroll
    for (int j = 0; j < 20; j++) {
        int idx = base + j;
        if (idx < NNODES) row_ptr[idx] = run;
        run += vals[j];
    }
    if (t == 1023) row_ptr[NNODES] = sdata[1023];
}

__global__ void fill_kernel(const int* __restrict__ ei,
                            const int* __restrict__ row_ptr,
                            int* __restrict__ cursor,
                            int2* __restrict__ csr)   // {src, eid}
{
    int e = blockIdx.x * blockDim.x + threadIdx.x;
    if (e >= NEDGES) return;
    int dst = ei[NEDGES + e];
    int p = row_ptr[dst] + atomicAdd(&cursor[dst], 1);
    csr[p] = make_int2(ei[e], e);
}

__global__ void dinv_kernel(const int* __restrict__ row_ptr, float* __restrict__ dinv) {
    int i = blockIdx.x * blockDim.x + threadIdx.x;
    if (i < NNODES) {
        int deg = row_ptr[i + 1] - row_ptr[i] + 1;   // + self loop
        dinv[i] = rsqrtf((float)deg);
    }
}

// ---------------- packing ----------------
__global__ void pad_copy_kernel(const float* __restrict__ src,
                                unsigned short* __restrict__ dst,
                                int valid_rows, int cols, long total)
{
    long idx = (long)blockIdx.x * blockDim.x + threadIdx.x;
    if (idx >= total) return;
    int n = (int)(idx / cols);
    dst[idx] = (n < valid_rows) ? f2b(src[idx]) : (unsigned short)0;
}

// New interleaved P column layout (groups of 4 columns per channel pair):
//   cols [0,1024):   group cp: [f_dst[2cp], f_dst[2cp+1], s_dst[2cp], s_dst[2cp+1]]
//   cols [1024,2048): same for src projections
// -> per-edge gather reads ONE dwordx2 instead of two dwords 2KB apart.
__global__ void pack_cgw_kernel(const float* __restrict__ Wf,
                                const float* __restrict__ Ws,
                                unsigned short* __restrict__ out)
{
    int idx = blockIdx.x * blockDim.x + threadIdx.x;
    if (idx >= 2048 * 512) return;
    int j = idx >> 9;          // output column (wpack row) 0..2047
    int k = idx & 511;         // K index
    int half = (j >= 1024);    // 0 = dst block, 1 = src block
    int jj = j & 1023;
    int c  = (jj >> 2) * 2 + (jj & 1);   // channel
    int fs = (jj >> 1) & 1;              // 0 = f, 1 = s
    const float* W = fs ? Ws : Wf;
    float v = W[(size_t)(half ? 512 + k : k) * 512 + c];
    out[idx] = f2b(v);
}

__global__ void pack_t_kernel(const float* __restrict__ W,
                              unsigned short* __restrict__ WT,
                              int K, int Nout)
{
    long idx = (long)blockIdx.x * blockDim.x + threadIdx.x;
    if (idx >= (long)K * Nout) return;
    int j = (int)(idx / K);
    int k = (int)(idx % K);
    WT[idx] = f2b(W[(size_t)k * Nout + j]);
}

// ---------------- CGConv gather ----------------
// P (bf16) with interleaved columns (see pack_cgw_kernel).
// 4 nodes per block to amortize the register-resident W_e preload.
// CSR entry + edge-attr + P-row base are wave-uniform -> readfirstlane so the
// edge attrs become scalar loads and per-lane 64-bit addressing disappears.
#define CG_NPB 4
__global__ __launch_bounds__(256, 1) void cg_gather_kernel(
    const unsigned short* __restrict__ P,
    const int* __restrict__ row_ptr,
    const int2* __restrict__ csr,
    const float* __restrict__ ea,
    const float* __restrict__ Wf,   // [1040,512], rows 1024.. = W_e
    const float* __restrict__ Ws,
    const float* __restrict__ bfv,
    const float* __restrict__ bsv,
    const float* __restrict__ g,
    const float* __restrict__ be,
    const float* __restrict__ xresf,          // fp32 [NNODES,512] or null
    const unsigned short* __restrict__ xresb, // bf16 [NPAD,512] or null
    unsigned short* __restrict__ hout)
{
    const int tid = threadIdx.x;
    const int c0  = tid * 2;
    const int nbase = blockIdx.x * CG_NPB;

    // weights resident in VGPRs (64 regs), loaded once per block
    f32x2 wf[16], wsv[16];
#pragma unroll
    for (int k = 0; k < 16; k++) {
        const size_t rb = (size_t)(1024 + k) * 512;
        wf[k]  = *(const f32x2*)&Wf[rb + c0];
        wsv[k] = *(const f32x2*)&Ws[rb + c0];
    }
    const f32x2 bfx = *(const f32x2*)&bfv[c0];
    const f32x2 bsx = *(const f32x2*)&bsv[c0];
    const f32x2 gv  = *(const f32x2*)&g[c0];
    const f32x2 bev = *(const f32x2*)&be[c0];
    const float rs = rsqrtf(1.f + 1e-5f);

    for (int n = nbase; n < nbase + CG_NPB; n++) {
        if (n >= NNODES) {
            *(unsigned int*)&hout[(size_t)n * 512 + c0] = 0;
            continue;
        }
        const unsigned short* Pd = P + (size_t)n * 2048;
        const uint2 qb = *(const uint2*)(Pd + c0 * 2);
        const f32x2 baseF = unpack2(qb.x) + bfx;
        const f32x2 baseS = unpack2(qb.y) + bsx;

        f32x2 acc = {0.f, 0.f};
        const int i0 = row_ptr[n], i1 = row_ptr[n + 1];

        if (i0 < i1) {
            // prologue: load edge i0 (uniform parts via SGPRs)
            int2 se = csr[i0];
            int sx = __builtin_amdgcn_readfirstlane(se.x);
            int sy = __builtin_amdgcn_readfirstlane(se.y);
            const float4* ep = (const float4*)(ea + (size_t)sy * 16);
            float4 e0 = ep[0], e1 = ep[1], e2 = ep[2], e3 = ep[3];
            uint2 q = *(const uint2*)(P + (size_t)sx * 2048 + 1024 + c0 * 2);

            for (int i = i0; i < i1; i++) {
                float4 c0v = e0, c1v = e1, c2v = e2, c3v = e3;
                uint2  cq  = q;
                if (i + 1 < i1) {
                    int2 se2 = csr[i + 1];
                    int sx2 = __builtin_amdgcn_readfirstlane(se2.x);
                    int sy2 = __builtin_amdgcn_readfirstlane(se2.y);
                    const float4* ep2 = (const float4*)(ea + (size_t)sy2 * 16);
                    e0 = ep2[0]; e1 = ep2[1]; e2 = ep2[2]; e3 = ep2[3];
                    q = *(const uint2*)(P + (size_t)sx2 * 2048 + 1024 + c0 * 2);
                }
                f32x2 f = baseF + unpack2(cq.x);
                f32x2 s = baseS + unpack2(cq.y);
                const float ek[16] = {c0v.x, c0v.y, c0v.z, c0v.w,
                                      c1v.x, c1v.y, c1v.z, c1v.w,
                                      c2v.x, c2v.y, c2v.z, c2v.w,
                                      c3v.x, c3v.y, c3v.z, c3v.w};
#pragma unroll
                for (int k = 0; k < 16; k++) {
                    f32x2 ev = {ek[k], ek[k]};
                    f = __builtin_elementwise_fma(ev, wf[k], f);
                    s = __builtin_elementwise_fma(ev, wsv[k], s);
                }
                float sp0 = __logf(1.f + __expf(s.x));
                float sp1 = __logf(1.f + __expf(s.y));
                float sg0 = __builtin_amdgcn_rcpf(1.f + __expf(-f.x));
                float sg1 = __builtin_amdgcn_rcpf(1.f + __expf(-f.y));
                acc.x = fmaf(sp0, sg0, acc.x);
                acc.y = fmaf(sp1, sg1, acc.y);
            }
        }
        // fused BN(eval) + residual + ReLU
        f32x2 res;
        if (xresf) {
            res = *(const f32x2*)&xresf[(size_t)n * 512 + c0];
        } else {
            res = unpack2(*(const unsigned int*)&xresb[(size_t)n * 512 + c0]);
        }
        float v0 = fmaxf(acc.x * (gv.x * rs) + bev.x + res.x, 0.f);
        float v1 = fmaxf(acc.y * (gv.y * rs) + bev.y + res.y, 0.f);
        unsigned int packed = (unsigned int)f2b(v0) | ((unsigned int)f2b(v1) << 16);
        *(unsigned int*)&hout[(size_t)n * 512 + c0] = packed;
    }
}

// ---------------- GCN gather (2 nodes/block, 2 ch/thread, scalarized src) ----------------
__global__ __launch_bounds__(256) void gcn_gather_kernel(
    const unsigned short* __restrict__ pre,   // bf16 [NPAD,256]
    const int* __restrict__ row_ptr,
    const int2* __restrict__ csr,
    const float* __restrict__ dinv,
    const float* __restrict__ b,
    unsigned short* __restrict__ hout,  // bf16 [NPAD,256]
    float* __restrict__ doutf)          // fp32 [NNODES,256] or null
{
    const int tid = threadIdx.x;
    const int n = blockIdx.x * 2 + (tid >> 7);   // waves 0-1 -> node A, 2-3 -> node B
    const int c = (tid & 127) * 2;
    if (n >= NNODES) {
        if (n < NPAD) *(unsigned int*)&hout[(size_t)n * 256 + c] = 0;
        return;
    }
    const float din = dinv[n];
    f32x2 acc = {0.f, 0.f};
    const int i0 = row_ptr[n], i1 = row_ptr[n + 1];
    if (i0 < i1) {
        int sx = __builtin_amdgcn_readfirstlane(csr[i0].x);
        float dv = dinv[sx];
        unsigned int pv = *(const unsigned int*)&pre[(size_t)sx * 256 + c];
        for (int i = i0; i < i1; i++) {
            float cdv = dv; unsigned int cpv = pv;
            if (i + 1 < i1) {
                int sx2 = __builtin_amdgcn_readfirstlane(csr[i + 1].x);
                dv = dinv[sx2];
                pv = *(const unsigned int*)&pre[(size_t)sx2 * 256 + c];
            }
            f32x2 p = unpack2(cpv);
            acc.x = fmaf(cdv, p.x, acc.x);
            acc.y = fmaf(cdv, p.y, acc.y);
        }
    }
    f32x2 self = unpack2(*(const unsigned int*)&pre[(size_t)n * 256 + c]);
    const f32x2 bv = *(const f32x2*)&b[c];
    float v0 = fmaxf(fmaf(acc.x, din, din * din * self.x) + bv.x, 0.f);
    float v1 = fmaxf(fmaf(acc.y, din, din * din * self.y) + bv.y, 0.f);
    *(unsigned int*)&hout[(size_t)n * 256 + c] =
        (unsigned int)f2b(v0) | ((unsigned int)f2b(v1) << 16);
    if (doutf) {
        f32x2 vv = {v0, v1};
        *(f32x2*)&doutf[(size_t)n * 256 + c] = vv;
    }
}

// ---------------- MLP ----------------
__global__ void build_zc_kernel(const unsigned short* __restrict__ h4,
                                const float* __restrict__ goal,
                                unsigned short* __restrict__ zc)
{
    long idx = (long)blockIdx.x * blockDim.x + threadIdx.x;
    if (idx >= (long)NPAD * 768) return;
    int n = (int)(idx / 768);
    int c = (int)(idx % 768);
    unsigned short v = 0;
    if (n < NNODES)
        v = (c < 256) ? h4[(size_t)n * 256 + c]
                      : f2b(goal[(size_t)n * 512 + (c - 256)]);
    zc[idx] = v;
}

__global__ __launch_bounds__(256) void final_dot_kernel(
    const unsigned short* __restrict__ t,
    const float* __restrict__ Wd2,
    const float* __restrict__ bd2,
    float* __restrict__ pred)
{
    const int lane = threadIdx.x & 63;
    const int wid  = threadIdx.x >> 6;
    float w[8];
#pragma unroll
    for (int i = 0; i < 8; i++) w[i] = Wd2[lane * 8 + i];
    const float bd = bd2[0];
    for (int n = blockIdx.x * 4 + wid; n < NNODES; n += gridDim.x * 4) {
        const unsigned short* tp = t + (size_t)n * 512 + lane * 8;
        float s = 0.f;
#pragma unroll
        for (int i = 0; i < 8; i++) s = fmaf(b2f(tp[i]), w[i], s);
#pragma unroll
        for (int off = 32; off; off >>= 1) s += __shfl_xor(s, off, 64);
        if (lane == 0) pred[n] = s + bd;
    }
}

// ---------------- launcher ----------------
extern "C" void kernel_launch(void* const* d_in, const int* in_sizes, int n_in,
                              void* d_out, int out_size, void* d_ws, size_t ws_size,
                              hipStream_t stream)
{
    (void)in_sizes; (void)n_in; (void)out_size; (void)ws_size;
    const float* x    = (const float*)d_in[0];
    const int*   ei   = (const int*)d_in[1];
    const float* ea   = (const float*)d_in[2];
    const float* goal = (const float*)d_in[3];
    const float* Wf1  = (const float*)d_in[4];
    const float* bf1  = (const float*)d_in[5];
    const float* Ws1  = (const float*)d_in[6];
    const float* bs1  = (const float*)d_in[7];
    const float* g1   = (const float*)d_in[8];
    const float* be1  = (const float*)d_in[9];
    const float* Wf2  = (const float*)d_in[10];
    const float* bf2  = (const float*)d_in[11];
    const float* Ws2  = (const float*)d_in[12];
    const float* bs2  = (const float*)d_in[13];
    const float* g2   = (const float*)d_in[14];
    const float* be2  = (const float*)d_in[15];
    const float* W3   = (const float*)d_in[16];
    const float* b3   = (const float*)d_in[17];
    const float* W4   = (const float*)d_in[18];
    const float* b4   = (const float*)d_in[19];
    const float* Wd1  = (const float*)d_in[20];
    const float* bd1  = (const float*)d_in[21];
    const float* Wd2  = (const float*)d_in[22];
    const float* bd2  = (const float*)d_in[23];
    float* outp = (float*)d_out;   // fp32: [0..N) pred, [N..N+N*256) h

    char* ws = (char*)d_ws;
    size_t off = 0;
    auto alloc = [&](size_t bytes) -> char* {
        char* p = ws + off;
        off += (bytes + 255) & ~(size_t)255;
        return p;
    };
    unsigned short* P     = (unsigned short*)alloc((size_t)NPAD * 2048 * 2); // later zc + tb
    unsigned short* bufA  = (unsigned short*)alloc((size_t)NPAD * 512 * 2);  // xpad / h2 / h4
    unsigned short* bufB  = (unsigned short*)alloc((size_t)NPAD * 512 * 2);  // h1 / pre_b
    unsigned short* bufC  = (unsigned short*)alloc((size_t)NPAD * 512 * 2);  // h3
    unsigned short* wpack = (unsigned short*)alloc((size_t)2048 * 512 * 2);
    int*            counts  = (int*)alloc((size_t)NNODES * 4);
    int*            row_ptr = (int*)alloc((size_t)(NNODES + 1) * 4);
    int2*           csr     = (int2*)alloc((size_t)NEDGES * 8);
    float*          dinv    = (float*)alloc((size_t)NNODES * 4);

    unsigned short* xpad  = bufA;
    unsigned short* h1    = bufB;
    unsigned short* h2    = bufA;
    unsigned short* pre_b = bufB;
    unsigned short* h3    = bufC;
    unsigned short* h4    = bufA;
    unsigned short* zc    = P;
    unsigned short* tb    = P + (size_t)NPAD * 1024;

    const int B = 256;

    // ---- CSR build (by destination) + dinv ----
    hipMemsetAsync(counts, 0, (size_t)NNODES * 4, stream);
    count_kernel<<<(NEDGES + B - 1) / B, B, 0, stream>>>(ei, counts);
    scan_kernel<<<1, 1024, 0, stream>>>(counts, row_ptr);
    hipMemsetAsync(counts, 0, (size_t)NNODES * 4, stream);
    fill_kernel<<<(NEDGES + B - 1) / B, B, 0, stream>>>(ei, row_ptr, counts, csr);
    dinv_kernel<<<(NNODES + B - 1) / B, B, 0, stream>>>(row_ptr, dinv);

    {
        long tot = (long)NPAD * 512;
        pad_copy_kernel<<<(unsigned)((tot + B - 1) / B), B, 0, stream>>>(x, xpad, NNODES, 512, tot);
    }

    dim3 gBig(NPAD / 128, 2048 / 128);

    // ---- CGConv layer 1 ----
    pack_cgw_kernel<<<(2048 * 512 + B - 1) / B, B, 0, stream>>>(Wf1, Ws1, wpack);
    gemm_bt_kernel<<<gBig, B, 0, stream>>>(xpad, wpack, nullptr, P, NPAD, 2048, 512, nullptr);
    cg_gather_kernel<<<NPAD / CG_NPB, B, 0, stream>>>(P, row_ptr, csr, ea,
                                                      Wf1, Ws1, bf1, bs1, g1, be1,
                                                      x, nullptr, h1);

    // ---- CGConv layer 2 ----
    pack_cgw_kernel<<<(2048 * 512 + B - 1) / B, B, 0, stream>>>(Wf2, Ws2, wpack);
    gemm_bt_kernel<<<gBig, B, 0, stream>>>(h1, wpack, nullptr, P, NPAD, 2048, 512, nullptr);
    cg_gather_kernel<<<NPAD / CG_NPB, B, 0, stream>>>(P, row_ptr, csr, ea,
                                                      Wf2, Ws2, bf2, bs2, g2, be2,
                                                      nullptr, h1, h2);

    // ---- GCN layer 3 ----
    pack_t_kernel<<<(256 * 512 + B - 1) / B, B, 0, stream>>>(W3, wpack, 512, 256);
    gemm_bt_kernel<<<dim3(NPAD / 128, 2), B, 0, stream>>>(h2, wpack, nullptr, pre_b, NPAD, 256, 512, nullptr);
    gcn_gather_kernel<<<NPAD / 2, B, 0, stream>>>(pre_b, row_ptr, csr, dinv, b3, h3, (float*)nullptr);

    // ---- GCN layer 4 ----
    pack_t_kernel<<<(256 * 256 + B - 1) / B, B, 0, stream>>>(W4, wpack, 256, 256);
    gemm_bt_kernel<<<dim3(NPAD / 128, 2), B, 0, stream>>>(h3, wpack, nullptr, pre_b, NPAD, 256, 256, nullptr);
    gcn_gather_kernel<<<NPAD / 2, B, 0, stream>>>(pre_b, row_ptr, csr, dinv, b4, h4, outp + NNODES);

    // ---- distance MLP (bias+ReLU fused into GEMM epilogue) ----
    build_zc_kernel<<<(unsigned)(((long)NPAD * 768 + B - 1) / B), B, 0, stream>>>(h4, goal, zc);
    pack_t_kernel<<<(512 * 768 + B - 1) / B, B, 0, stream>>>(Wd1, wpack, 768, 512);
    gemm_bt_kernel<<<dim3(NPAD / 128, 4), B, 0, stream>>>(zc, wpack, nullptr, tb, NPAD, 512, 768, bd1);
    final_dot_kernel<<<512, B, 0, stream>>>(tb, Wd2, bd2, outp);
}